// Round 2
// baseline (311.240 us; speedup 1.0000x reference)
//
#include <hip/hip_runtime.h>

typedef __attribute__((ext_vector_type(8))) __bf16 bf16x8;
typedef __attribute__((ext_vector_type(4))) float f32x4;

#define DI __device__ __forceinline__

// float -> bf16 bits, round-to-nearest-even (epilogue use)
DI unsigned short f2bf(float x) {
  unsigned u = __float_as_uint(x);
  u += 0x7fffu + ((u >> 16) & 1u);
  return (unsigned short)(u >> 16);
}

// 8x fp32 -> bf16x8 via native casts (gfx950: v_cvt_pk_bf16_f32, RNE)
DI bf16x8 cvt8(f32x4 lo, f32x4 hi) {
  bf16x8 r;
  r[0] = (__bf16)lo.x; r[1] = (__bf16)lo.y; r[2] = (__bf16)lo.z; r[3] = (__bf16)lo.w;
  r[4] = (__bf16)hi.x; r[5] = (__bf16)hi.y; r[6] = (__bf16)hi.z; r[7] = (__bf16)hi.w;
  return r;
}

DI float tanh_fast(float x) {
  float ax = fabsf(x);
  float e = __expf(-2.0f * ax);
  float t = (1.0f - e) / (1.0f + e);
  return x < 0.0f ? -t : t;
}

// ---------------------------------------------------------------------------
// Kernel 0: W [512(k),256(n)] fp32 -> Wt [256(n),512(k)] bf16 (B^T layout).
// ---------------------------------------------------------------------------
__global__ void k_wt(const float* __restrict__ W, unsigned short* __restrict__ Wt) {
  int n = blockIdx.x;      // 0..255
  int t = threadIdx.x;     // 0..127
  int k = t * 4;
  ushort4 v;
  v.x = f2bf(W[(k + 0) * 256 + n]);
  v.y = f2bf(W[(k + 1) * 256 + n]);
  v.z = f2bf(W[(k + 2) * 256 + n]);
  v.w = f2bf(W[(k + 3) * 256 + n]);
  *(ushort4*)&Wt[n * 512 + k] = v;
}

// ---------------------------------------------------------------------------
// Kernel 1: projection GEMM, LDS-FREE. M=65536, K=512, N=256.
// Block = 128 rows x 256 cols, 1024 threads = 16 waves in 4x4 grid,
// wave-tile 32x64 (acc 2x4 f32x4 = 32 AGPR/lane).
// A fragments: fp32 direct from global (L1-reused across the 4 wn-waves),
// converted in-register. B fragments: bf16 direct from Wt (512 KB, L2-hot).
// NO __syncthreads in the K-loop — waves fully independent.
// ---------------------------------------------------------------------------
__global__ __launch_bounds__(1024, 4) void k_proj(
    const float* __restrict__ Alt, const float* __restrict__ Art,
    const unsigned short* __restrict__ Wt, const float* __restrict__ diag,
    unsigned short* __restrict__ Olt, unsigned short* __restrict__ Ort) {
  int bx = blockIdx.x;              // 0..511
  bool is_lt = bx < 256;
  int m0 = (is_lt ? bx : bx - 256) * 128;
  const float* A = (is_lt ? Alt : Art) + (size_t)m0 * 512;
  unsigned short* O = (is_lt ? Olt : Ort) + (size_t)m0 * 256;

  int tid  = threadIdx.x;
  int lane = tid & 63;
  int wid  = tid >> 6;              // 0..15
  int wmg  = wid >> 2;              // 0..3  -> 32-row group
  int wng  = wid & 3;               // 0..3  -> 64-col group
  int l15  = lane & 15;
  int quad = lane >> 4;

  // Per-lane base pointers (hoisted out of the loop)
  const float* a0 = A + (size_t)(wmg * 32 + 0 * 16 + l15) * 512 + quad * 8;
  const float* a1 = A + (size_t)(wmg * 32 + 1 * 16 + l15) * 512 + quad * 8;
  const unsigned short* bp[4];
#pragma unroll
  for (int nt = 0; nt < 4; nt++)
    bp[nt] = Wt + (size_t)(wng * 64 + nt * 16 + l15) * 512 + quad * 8;

  f32x4 zero = {0.0f, 0.0f, 0.0f, 0.0f};
  f32x4 acc[2][4];
#pragma unroll
  for (int i = 0; i < 2; i++)
#pragma unroll
    for (int j = 0; j < 4; j++) acc[i][j] = zero;

#pragma unroll 2
  for (int k0 = 0; k0 < 512; k0 += 32) {
    bf16x8 a[2], bb[4];
    {
      f32x4 lo0 = *(const f32x4*)(a0 + k0);
      f32x4 hi0 = *(const f32x4*)(a0 + k0 + 4);
      f32x4 lo1 = *(const f32x4*)(a1 + k0);
      f32x4 hi1 = *(const f32x4*)(a1 + k0 + 4);
      a[0] = cvt8(lo0, hi0);
      a[1] = cvt8(lo1, hi1);
    }
#pragma unroll
    for (int nt = 0; nt < 4; nt++)
      bb[nt] = *(const bf16x8*)(bp[nt] + k0);
#pragma unroll
    for (int mt = 0; mt < 2; mt++)
#pragma unroll
      for (int nt = 0; nt < 4; nt++)
        acc[mt][nt] = __builtin_amdgcn_mfma_f32_16x16x32_bf16(a[mt], bb[nt], acc[mt][nt], 0, 0, 0);
  }

  // Epilogue: tanh, diag scale (lt only), bf16 store.
  float dscale[4];
#pragma unroll
  for (int nt = 0; nt < 4; nt++)
    dscale[nt] = is_lt ? diag[wng * 64 + nt * 16 + l15] : 1.0f;

#pragma unroll
  for (int mt = 0; mt < 2; mt++) {
#pragma unroll
    for (int r = 0; r < 4; r++) {
      int row = wmg * 32 + mt * 16 + quad * 4 + r;
#pragma unroll
      for (int nt = 0; nt < 4; nt++) {
        int col = wng * 64 + nt * 16 + l15;
        O[(size_t)row * 256 + col] = f2bf(tanh_fast(acc[mt][nt][r]) * dscale[nt]);
      }
    }
  }
}

// ---------------------------------------------------------------------------
// Kernel 2: per-batch logits GEMM (lt_b @ rt_b^T, K=256) + exact softmax,
// LDS-FREE K-loop. Block = 64 L-rows x 512 R-cols, 1024 threads = 16 waves
// (2 row-halves x 8 col-groups), wave-tile 32x64, acc 32/lane.
// XCD swizzle: blocks with the same (blockIdx & 7) share batches, so each
// XCD's L2 only streams 8 batches of Lt/Rt (HBM fetch = ideal 32 MB).
// ---------------------------------------------------------------------------
__global__ __launch_bounds__(1024, 4) void k_attn(
    const unsigned short* __restrict__ Lt, const unsigned short* __restrict__ Rt,
    float* __restrict__ Out) {
  __shared__ float red[8][64];
  __shared__ float rowv[64];

  int bx = blockIdx.x;                       // 0..511
  int b  = (bx & 7) * 8 + ((bx >> 3) & 7);   // batch, XCD-co-located
  int l0 = (bx >> 6) * 64;                   // L-chunk
  const unsigned short* Lb = Lt + ((size_t)b * 512 + l0) * 256;
  const unsigned short* Rb = Rt + (size_t)b * 512 * 256;
  float* Ob = Out + ((size_t)b * 512 + l0) * 512;

  int tid  = threadIdx.x;
  int lane = tid & 63;
  int wid  = tid >> 6;              // 0..15
  int wmg  = wid >> 3;              // 0..1 -> 32-row half
  int wng  = wid & 7;               // 0..7 -> 64-col group
  int l15  = lane & 15;
  int quad = lane >> 4;

  const unsigned short* ap0 = Lb + (size_t)(wmg * 32 + 0 * 16 + l15) * 256 + quad * 8;
  const unsigned short* ap1 = Lb + (size_t)(wmg * 32 + 1 * 16 + l15) * 256 + quad * 8;
  const unsigned short* bp[4];
#pragma unroll
  for (int nt = 0; nt < 4; nt++)
    bp[nt] = Rb + (size_t)(wng * 64 + nt * 16 + l15) * 256 + quad * 8;

  f32x4 zero = {0.0f, 0.0f, 0.0f, 0.0f};
  f32x4 acc[2][4];
#pragma unroll
  for (int i = 0; i < 2; i++)
#pragma unroll
    for (int j = 0; j < 4; j++) acc[i][j] = zero;

#pragma unroll 2
  for (int k0 = 0; k0 < 256; k0 += 32) {
    bf16x8 a[2], bb[4];
    a[0] = *(const bf16x8*)(ap0 + k0);
    a[1] = *(const bf16x8*)(ap1 + k0);
#pragma unroll
    for (int nt = 0; nt < 4; nt++)
      bb[nt] = *(const bf16x8*)(bp[nt] + k0);
#pragma unroll
    for (int mt = 0; mt < 2; mt++)
#pragma unroll
      for (int nt = 0; nt < 4; nt++)
        acc[mt][nt] = __builtin_amdgcn_mfma_f32_16x16x32_bf16(a[mt], bb[nt], acc[mt][nt], 0, 0, 0);
  }

  // -------- softmax over the 512-wide row (split across 8 wn-groups) ------
  // 1) row max
#pragma unroll
  for (int mt = 0; mt < 2; mt++) {
#pragma unroll
    for (int r = 0; r < 4; r++) {
      float m = fmaxf(fmaxf(acc[mt][0][r], acc[mt][1][r]),
                      fmaxf(acc[mt][2][r], acc[mt][3][r]));
      m = fmaxf(m, __shfl_xor(m, 1));
      m = fmaxf(m, __shfl_xor(m, 2));
      m = fmaxf(m, __shfl_xor(m, 4));
      m = fmaxf(m, __shfl_xor(m, 8));
      if (l15 == 0) red[wng][wmg * 32 + mt * 16 + quad * 4 + r] = m;
    }
  }
  __syncthreads();
  if (tid < 64) {
    float m = red[0][tid];
#pragma unroll
    for (int w = 1; w < 8; w++) m = fmaxf(m, red[w][tid]);
    rowv[tid] = m;
  }
  __syncthreads();

  // 2) exp + row sum
#pragma unroll
  for (int mt = 0; mt < 2; mt++) {
#pragma unroll
    for (int r = 0; r < 4; r++) {
      float base = rowv[wmg * 32 + mt * 16 + quad * 4 + r];
      float s = 0.0f;
#pragma unroll
      for (int nt = 0; nt < 4; nt++) {
        float e = __expf(acc[mt][nt][r] - base);
        acc[mt][nt][r] = e;
        s += e;
      }
      s += __shfl_xor(s, 1);
      s += __shfl_xor(s, 2);
      s += __shfl_xor(s, 4);
      s += __shfl_xor(s, 8);
      if (l15 == 0) red[wng][wmg * 32 + mt * 16 + quad * 4 + r] = s;
    }
  }
  __syncthreads();
  if (tid < 64) {
    float s = red[0][tid];
#pragma unroll
    for (int w = 1; w < 8; w++) s += red[w][tid];
    rowv[tid] = 1.0f / s;
  }
  __syncthreads();

  // 3) scale + store fp32
#pragma unroll
  for (int mt = 0; mt < 2; mt++) {
#pragma unroll
    for (int r = 0; r < 4; r++) {
      int row = wmg * 32 + mt * 16 + quad * 4 + r;
      float inv = rowv[row];
#pragma unroll
      for (int nt = 0; nt < 4; nt++) {
        int col = wng * 64 + nt * 16 + l15;
        Ob[(size_t)row * 512 + col] = acc[mt][nt][r] * inv;
      }
    }
  }
}

// ---------------------------------------------------------------------------
extern "C" void kernel_launch(void* const* d_in, const int* in_sizes, int n_in,
                              void* d_out, int out_size, void* d_ws, size_t ws_size,
                              hipStream_t stream) {
  const float* lstm_lt = (const float*)d_in[0];   // (64,512,512)
  const float* lstm_rt = (const float*)d_in[1];   // (64,512,512)
  const float* W       = (const float*)d_in[2];   // (512,256)
  const float* diag    = (const float*)d_in[3];   // (256)
  float* out = (float*)d_out;                     // (64,512,512)

  // Workspace: Wt bf16 [256,512] | lt bf16 [32768,256] | rt bf16 [32768,256]
  unsigned short* Wt  = (unsigned short*)d_ws;
  unsigned short* Olt = (unsigned short*)((char*)d_ws + (size_t)256 * 512 * 2);
  unsigned short* Ort = Olt + (size_t)32768 * 256;

  k_wt<<<dim3(256), dim3(128), 0, stream>>>(W, Wt);
  k_proj<<<dim3(512), dim3(1024), 0, stream>>>(lstm_lt, lstm_rt, Wt, diag, Olt, Ort);
  k_attn<<<dim3(512), dim3(1024), 0, stream>>>(Olt, Ort, out);
}

// Round 3
// 207.997 us; speedup vs baseline: 1.4964x; 1.4964x over previous
//
#include <hip/hip_runtime.h>

typedef __attribute__((ext_vector_type(8))) __bf16 bf16x8;
typedef __attribute__((ext_vector_type(4))) float f32x4;

#define DI __device__ __forceinline__

// float -> bf16 bits, RNE
DI unsigned short f2bf(float x) {
  unsigned u = __float_as_uint(x);
  u += 0x7fffu + ((u >> 16) & 1u);
  return (unsigned short)(u >> 16);
}

DI bf16x8 cvt8(f32x4 lo, f32x4 hi) {
  bf16x8 r;
  r[0] = (__bf16)lo.x; r[1] = (__bf16)lo.y; r[2] = (__bf16)lo.z; r[3] = (__bf16)lo.w;
  r[4] = (__bf16)hi.x; r[5] = (__bf16)hi.y; r[6] = (__bf16)hi.z; r[7] = (__bf16)hi.w;
  return r;
}

DI float tanh_fast(float x) {
  float ax = fabsf(x);
  float e = __expf(-2.0f * ax);
  float t = (1.0f - e) / (1.0f + e);
  return x < 0.0f ? -t : t;
}

// async global->LDS, 16 B per lane. LDS dst = wave-uniform base + lane*16.
DI void glds16(const void* gptr, void* lptr) {
  __builtin_amdgcn_global_load_lds(
      (const __attribute__((address_space(1))) unsigned int*)gptr,
      (__attribute__((address_space(3))) unsigned int*)lptr, 16, 0, 0);
}

// ---------------------------------------------------------------------------
// Kernel 0: W [512(k),256(n)] fp32 -> Wt [256(n),512(k)] bf16 (B^T layout).
// ---------------------------------------------------------------------------
__global__ void k_wt(const float* __restrict__ W, unsigned short* __restrict__ Wt) {
  int n = blockIdx.x;
  int t = threadIdx.x;     // 0..127
  int k = t * 4;
  ushort4 v;
  v.x = f2bf(W[(k + 0) * 256 + n]);
  v.y = f2bf(W[(k + 1) * 256 + n]);
  v.z = f2bf(W[(k + 2) * 256 + n]);
  v.w = f2bf(W[(k + 3) * 256 + n]);
  *(ushort4*)&Wt[n * 512 + k] = v;
}

// ---------------------------------------------------------------------------
// Kernel 1: projection GEMM, m97-style. M=65536, K=512, N=256.
// Block 128x256, BK=64, 8 waves (2x4 of 64x64 tiles).
// A staged as RAW FP32 via global_load_lds (32 KB/step), converted to bf16 at
// fragment read.  B staged bf16 via global_load_lds (32 KB/step).
// XOR chunk swizzle folded into the per-lane GLOBAL source address (glds LDS
// side must be flat lane*16), so frag ds_reads spread across all 32 banks.
// LDS 64 KB -> 2 blocks/CU; launch_bounds(512,4) keeps regs <=128.
// ---------------------------------------------------------------------------
__global__ __launch_bounds__(512, 4) void k_proj(
    const float* __restrict__ Alt, const float* __restrict__ Art,
    const unsigned short* __restrict__ Wt, const float* __restrict__ diag,
    unsigned short* __restrict__ Olt, unsigned short* __restrict__ Ort) {
  // As: 128 rows x 64 k fp32, row = 256 B = 16 chunks of 16 B, swizzled.
  // Bs: 256 rows x 64 k bf16, row = 128 B = 8 chunks of 16 B, swizzled.
  __shared__ __align__(16) float As[128 * 64];
  __shared__ __align__(16) unsigned short Bs[256 * 64];

  int bx = blockIdx.x;              // 0..511
  bool is_lt = bx < 256;
  int m0 = (is_lt ? bx : bx - 256) * 128;
  const char* Abase = (const char*)((is_lt ? Alt : Art) + (size_t)m0 * 512);
  unsigned short* O = (is_lt ? Olt : Ort) + (size_t)m0 * 256;

  int tid  = threadIdx.x;
  int lane = tid & 63;
  int wid  = tid >> 6;              // 0..7
  int wm   = wid >> 2;              // 0..1
  int wn   = wid & 3;               // 0..3
  int l15  = lane & 15;
  int quad = lane >> 4;
  int r7   = l15 & 7;

  // glds per-lane source offsets (within a 4-row / 8-row group, k-window 0)
  int lr4 = lane >> 4, c16 = lane & 15;
  int aoff = lr4 * 2048 + ((c16 ^ lr4) << 4);          // A: row stride 2048 B
  int lr8 = lane >> 3, s8 = lane & 7;
  int boff = lr8 * 1024 + ((s8 ^ lr8) << 4);           // B: row stride 1024 B

  const char* Bbase = (const char*)Wt;
  char* AsB = (char*)As;
  char* BsB = (char*)Bs;

  f32x4 zero = {0.0f, 0.0f, 0.0f, 0.0f};
  f32x4 acc[4][4];
#pragma unroll
  for (int i = 0; i < 4; i++)
#pragma unroll
    for (int j = 0; j < 4; j++) acc[i][j] = zero;

  for (int k0 = 0; k0 < 512; k0 += 64) {
    // --- stage A (fp32): 32 insts, 4 per wave; inst j covers rows 4j..4j+3
#pragma unroll
    for (int i = 0; i < 4; i++) {
      int j = wid * 4 + i;
      glds16(Abase + (size_t)j * 8192 + (size_t)k0 * 4 + (aoff ^ ((j & 1) << 6)),
             AsB + j * 1024);
    }
    // --- stage B (bf16): 32 insts, 4 per wave; inst j covers rows 8j..8j+7
#pragma unroll
    for (int i = 0; i < 4; i++) {
      int j = wid * 4 + i;
      glds16(Bbase + (size_t)j * 8192 + (size_t)k0 * 2 + boff, BsB + j * 1024);
    }
    __syncthreads();   // drains glds (vmcnt(0) before s_barrier)

#pragma unroll
    for (int ks = 0; ks < 2; ks++) {
      bf16x8 a[4], b[4];
#pragma unroll
      for (int mt = 0; mt < 4; mt++) {
        int row = wm * 64 + mt * 16 + l15;
        int c0 = ks * 8 + quad * 2;
        f32x4 lo = *(const f32x4*)(AsB + row * 256 + (((c0    ) ^ r7) << 4));
        f32x4 hi = *(const f32x4*)(AsB + row * 256 + (((c0 + 1) ^ r7) << 4));
        a[mt] = cvt8(lo, hi);
      }
#pragma unroll
      for (int nt = 0; nt < 4; nt++) {
        int row = wn * 64 + nt * 16 + l15;
        int c = ks * 4 + quad;
        b[nt] = *(const bf16x8*)(BsB + row * 128 + ((c ^ r7) << 4));
      }
#pragma unroll
      for (int mt = 0; mt < 4; mt++)
#pragma unroll
        for (int nt = 0; nt < 4; nt++)
          acc[mt][nt] = __builtin_amdgcn_mfma_f32_16x16x32_bf16(a[mt], b[nt], acc[mt][nt], 0, 0, 0);
    }
    __syncthreads();   // protect LDS before next step's staging
  }

  // Epilogue: tanh, diag scale (lt only), bf16 store.
  float dscale[4];
#pragma unroll
  for (int nt = 0; nt < 4; nt++)
    dscale[nt] = is_lt ? diag[wn * 64 + nt * 16 + l15] : 1.0f;

#pragma unroll
  for (int mt = 0; mt < 4; mt++) {
#pragma unroll
    for (int r = 0; r < 4; r++) {
      int row = wm * 64 + mt * 16 + quad * 4 + r;
#pragma unroll
      for (int nt = 0; nt < 4; nt++) {
        int col = wn * 64 + nt * 16 + l15;
        O[(size_t)row * 256 + col] = f2bf(tanh_fast(acc[mt][nt][r]) * dscale[nt]);
      }
    }
  }
}

// ---------------------------------------------------------------------------
// Kernel 2: per-batch logits (lt_b @ rt_b^T, K=256) + fused exact softmax.
// Block 64(L) x 512(R), 8 waves (64x64 tiles, wid = col-group), BK=64,
// glds-staged swizzled LDS (Ls 8 KB + Rs 64 KB). XCD batch swizzle.
// ---------------------------------------------------------------------------
__global__ __launch_bounds__(512, 4) void k_attn(
    const unsigned short* __restrict__ Lt, const unsigned short* __restrict__ Rt,
    float* __restrict__ Out) {
  __shared__ __align__(16) unsigned short Ls[64 * 64];    // 8 KB
  __shared__ __align__(16) unsigned short Rs[512 * 64];   // 64 KB
  __shared__ float red[8][64];
  __shared__ float rowv[64];

  int bx = blockIdx.x;                       // 0..511
  int b  = (bx & 7) * 8 + ((bx >> 3) & 7);   // batch, XCD-co-located
  int l0 = (bx >> 6) * 64;
  const char* Lb = (const char*)(Lt + ((size_t)b * 512 + l0) * 256);
  const char* Rb = (const char*)(Rt + (size_t)b * 512 * 256);
  float* Ob = Out + ((size_t)b * 512 + l0) * 512;

  int tid  = threadIdx.x;
  int lane = tid & 63;
  int wid  = tid >> 6;              // 0..7 -> 64-col group
  int l15  = lane & 15;
  int quad = lane >> 4;
  int r7   = l15 & 7;

  int lr8 = lane >> 3, s8 = lane & 7;
  int goff = lr8 * 512 + ((s8 ^ lr8) << 4);  // row stride 512 B (256 bf16)

  char* LsB = (char*)Ls;
  char* RsB = (char*)Rs;

  f32x4 zero = {0.0f, 0.0f, 0.0f, 0.0f};
  f32x4 acc[4][4];
#pragma unroll
  for (int i = 0; i < 4; i++)
#pragma unroll
    for (int j = 0; j < 4; j++) acc[i][j] = zero;

  for (int k0 = 0; k0 < 256; k0 += 64) {
    // Ls: 8 insts total, 1 per wave (rows 8*wid..8*wid+7)
    glds16(Lb + (size_t)wid * 4096 + (size_t)k0 * 2 + goff, LsB + wid * 1024);
    // Rs: 64 insts, 8 per wave
#pragma unroll
    for (int i = 0; i < 8; i++) {
      int j = wid * 8 + i;
      glds16(Rb + (size_t)j * 4096 + (size_t)k0 * 2 + goff, RsB + j * 1024);
    }
    __syncthreads();

#pragma unroll
    for (int ks = 0; ks < 2; ks++) {
      bf16x8 a[4], bb[4];
#pragma unroll
      for (int mt = 0; mt < 4; mt++) {
        int row = mt * 16 + l15;
        int c = ks * 4 + quad;
        a[mt] = *(const bf16x8*)(LsB + row * 128 + ((c ^ r7) << 4));
      }
#pragma unroll
      for (int nt = 0; nt < 4; nt++) {
        int row = wid * 64 + nt * 16 + l15;
        int c = ks * 4 + quad;
        bb[nt] = *(const bf16x8*)(RsB + row * 128 + ((c ^ r7) << 4));
      }
#pragma unroll
      for (int mt = 0; mt < 4; mt++)
#pragma unroll
        for (int nt = 0; nt < 4; nt++)
          acc[mt][nt] = __builtin_amdgcn_mfma_f32_16x16x32_bf16(a[mt], bb[nt], acc[mt][nt], 0, 0, 0);
    }
    __syncthreads();
  }

  // -------- softmax over the 512-wide row (8 col-groups) --------
#pragma unroll
  for (int mt = 0; mt < 4; mt++) {
#pragma unroll
    for (int r = 0; r < 4; r++) {
      float m = fmaxf(fmaxf(acc[mt][0][r], acc[mt][1][r]),
                      fmaxf(acc[mt][2][r], acc[mt][3][r]));
      m = fmaxf(m, __shfl_xor(m, 1));
      m = fmaxf(m, __shfl_xor(m, 2));
      m = fmaxf(m, __shfl_xor(m, 4));
      m = fmaxf(m, __shfl_xor(m, 8));
      if (l15 == 0) red[wid][mt * 16 + quad * 4 + r] = m;
    }
  }
  __syncthreads();
  if (tid < 64) {
    float m = red[0][tid];
#pragma unroll
    for (int w = 1; w < 8; w++) m = fmaxf(m, red[w][tid]);
    rowv[tid] = m;
  }
  __syncthreads();

#pragma unroll
  for (int mt = 0; mt < 4; mt++) {
#pragma unroll
    for (int r = 0; r < 4; r++) {
      float base = rowv[mt * 16 + quad * 4 + r];
      float s = 0.0f;
#pragma unroll
      for (int nt = 0; nt < 4; nt++) {
        float e = __expf(acc[mt][nt][r] - base);
        acc[mt][nt][r] = e;
        s += e;
      }
      s += __shfl_xor(s, 1);
      s += __shfl_xor(s, 2);
      s += __shfl_xor(s, 4);
      s += __shfl_xor(s, 8);
      if (l15 == 0) red[wid][mt * 16 + quad * 4 + r] = s;
    }
  }
  __syncthreads();
  if (tid < 64) {
    float s = red[0][tid];
#pragma unroll
    for (int w = 1; w < 8; w++) s += red[w][tid];
    rowv[tid] = 1.0f / s;
  }
  __syncthreads();

#pragma unroll
  for (int mt = 0; mt < 4; mt++) {
#pragma unroll
    for (int r = 0; r < 4; r++) {
      int row = mt * 16 + quad * 4 + r;
      float inv = rowv[row];
#pragma unroll
      for (int nt = 0; nt < 4; nt++) {
        int col = wid * 64 + nt * 16 + l15;
        Ob[(size_t)row * 512 + col] = acc[mt][nt][r] * inv;
      }
    }
  }
}

// ---------------------------------------------------------------------------
extern "C" void kernel_launch(void* const* d_in, const int* in_sizes, int n_in,
                              void* d_out, int out_size, void* d_ws, size_t ws_size,
                              hipStream_t stream) {
  const float* lstm_lt = (const float*)d_in[0];   // (64,512,512)
  const float* lstm_rt = (const float*)d_in[1];   // (64,512,512)
  const float* W       = (const float*)d_in[2];   // (512,256)
  const float* diag    = (const float*)d_in[3];   // (256)
  float* out = (float*)d_out;                     // (64,512,512)

  // Workspace: Wt bf16 [256,512] | lt bf16 [32768,256] | rt bf16 [32768,256]
  unsigned short* Wt  = (unsigned short*)d_ws;
  unsigned short* Olt = (unsigned short*)((char*)d_ws + (size_t)256 * 512 * 2);
  unsigned short* Ort = Olt + (size_t)32768 * 256;

  k_wt<<<dim3(256), dim3(128), 0, stream>>>(W, Wt);
  k_proj<<<dim3(512), dim3(512), 0, stream>>>(lstm_lt, lstm_rt, Wt, diag, Olt, Ort);
  k_attn<<<dim3(512), dim3(512), 0, stream>>>(Olt, Ort, out);
}